// Round 1
// baseline (543.668 us; speedup 1.0000x reference)
//
#include <hip/hip_runtime.h>
#include <hip/hip_bf16.h>

#define NNODES 100000
#define NEDGES 1600000
#define KDIM 256
#define ODIM 128
#define NB_SCAN 98  // ceil(100000 / 1024)

typedef __attribute__((ext_vector_type(8))) short short8;
typedef __attribute__((ext_vector_type(4))) float floatx4;

// round-to-nearest-even f32 -> bf16 (inputs are finite Gaussians; no NaN handling needed)
static __device__ __forceinline__ short f2bf(float f) {
  union { float f; unsigned u; } x; x.f = f;
  unsigned r = (x.u + 0x7fffu + ((x.u >> 16) & 1u)) >> 16;
  return (short)r;
}

__global__ void conv_w_kernel(const float* __restrict__ W, short* __restrict__ Wb) {
  int i = blockIdx.x * 256 + threadIdx.x;
  if (i < ODIM * KDIM) Wb[i] = f2bf(W[i]);
}

__global__ void hist_kernel(const int* __restrict__ rows, int* __restrict__ counts) {
  int i = blockIdx.x * 256 + threadIdx.x;
  if (i < NEDGES) atomicAdd(&counts[rows[i]], 1);
}

// per-1024-chunk exclusive scan + chunk totals
__global__ void scan1_kernel(const int* __restrict__ counts, int* __restrict__ chunkExcl,
                             int* __restrict__ blockSums) {
  __shared__ int s[256];
  int t = threadIdx.x;
  int base = blockIdx.x * 1024 + t * 4;
  int v[4];
#pragma unroll
  for (int j = 0; j < 4; j++) {
    int idx = base + j;
    v[j] = (idx < NNODES) ? counts[idx] : 0;
  }
  int sum = v[0] + v[1] + v[2] + v[3];
  s[t] = sum;
  __syncthreads();
  for (int o = 1; o < 256; o <<= 1) {
    int add = (t >= o) ? s[t - o] : 0;
    __syncthreads();
    s[t] += add;
    __syncthreads();
  }
  int run = s[t] - sum;  // exclusive prefix of this thread's 4 elements within chunk
#pragma unroll
  for (int j = 0; j < 4; j++) {
    int idx = base + j;
    if (idx < NNODES) chunkExcl[idx] = run;
    run += v[j];
  }
  if (t == 255) blockSums[blockIdx.x] = s[255];
}

// single-block exclusive scan of the 98 chunk totals; also writes offsets[NNODES] = total
__global__ void scan2_kernel(const int* __restrict__ blockSums, int* __restrict__ blockBase,
                             int* __restrict__ offsets) {
  __shared__ int s[128];
  int t = threadIdx.x;
  int v = (t < NB_SCAN) ? blockSums[t] : 0;
  s[t] = v;
  __syncthreads();
  for (int o = 1; o < 128; o <<= 1) {
    int add = (t >= o) ? s[t - o] : 0;
    __syncthreads();
    s[t] += add;
    __syncthreads();
  }
  if (t < NB_SCAN) blockBase[t] = s[t] - v;
  if (t == 127) offsets[NNODES] = s[127];
}

__global__ void scan3_kernel(const int* __restrict__ chunkExcl, const int* __restrict__ blockBase,
                             int* __restrict__ offsets, int* __restrict__ cursor) {
  int i = blockIdx.x * 256 + threadIdx.x;
  if (i < NNODES) {
    int o = chunkExcl[i] + blockBase[i >> 10];
    offsets[i] = o;
    cursor[i] = o;
  }
}

__global__ void scatter_kernel(const int* __restrict__ rows, const int* __restrict__ cols,
                               const float* __restrict__ vals, int* __restrict__ cursor,
                               int* __restrict__ sCol, float* __restrict__ sVal) {
  int i = blockIdx.x * 256 + threadIdx.x;
  if (i < NEDGES) {
    int r = rows[i];
    int p = atomicAdd(&cursor[r], 1);
    sCol[p] = cols[i];
    sVal[p] = vals[i];
  }
}

// H = bf16(X @ W^T + b). Block = 256 (4 waves); each wave owns a 16-row strip,
// all 8 n-tiles (128 cols). A-frag: X[m=lane&15][k0 + quad*8 + j] (fp32 load + cvt).
// B-frag: Wb[n=lane&15(+16t)][k0 + quad*8 + j] (16 B bf16 load).
// D: col = lane&15, row = quad*4 + reg  [m89-verified layout]
__global__ __launch_bounds__(256) void gemm_kernel(const float* __restrict__ X,
                                                   const short* __restrict__ Wb,
                                                   const float* __restrict__ bias,
                                                   unsigned short* __restrict__ H) {
  const int lane = threadIdx.x & 63;
  const int wave = threadIdx.x >> 6;
  const int l16 = lane & 15;
  const int quad = lane >> 4;
  const int rowBase = blockIdx.x * 64 + wave * 16;
  const int arow = rowBase + l16;

  floatx4 acc[8];
#pragma unroll
  for (int t = 0; t < 8; t++) acc[t] = (floatx4){0.f, 0.f, 0.f, 0.f};

  for (int k0 = 0; k0 < KDIM; k0 += 32) {
    const int k = k0 + quad * 8;
    short8 a;
    if (arow < NNODES) {
      const float4* xp = (const float4*)(X + (size_t)arow * KDIM + k);
      float4 x0 = xp[0];
      float4 x1 = xp[1];
      a[0] = f2bf(x0.x); a[1] = f2bf(x0.y); a[2] = f2bf(x0.z); a[3] = f2bf(x0.w);
      a[4] = f2bf(x1.x); a[5] = f2bf(x1.y); a[6] = f2bf(x1.z); a[7] = f2bf(x1.w);
    } else {
      a = (short8){0, 0, 0, 0, 0, 0, 0, 0};
    }
#pragma unroll
    for (int t = 0; t < 8; t++) {
      short8 b = *(const short8*)(Wb + (t * 16 + l16) * KDIM + k);
      acc[t] = __builtin_amdgcn_mfma_f32_16x16x32_bf16(a, b, acc[t], 0, 0, 0);
    }
  }

#pragma unroll
  for (int t = 0; t < 8; t++) {
    const int col = t * 16 + l16;
    const float bv = bias[col];
#pragma unroll
    for (int r = 0; r < 4; r++) {
      const int row = rowBase + quad * 4 + r;
      if (row < NNODES) H[(size_t)row * ODIM + col] = (unsigned short)f2bf(acc[t][r] + bv);
    }
  }
}

// One wave per output row. Lane owns channels {2*lane, 2*lane+1} (one uint = 2 bf16
// per gathered H row -> 256 B coalesced per edge). fp32 accumulate, float2 store.
__global__ __launch_bounds__(256) void spmm_kernel(const int* __restrict__ offsets,
                                                   const int* __restrict__ sCol,
                                                   const float* __restrict__ sVal,
                                                   const unsigned* __restrict__ H2,
                                                   float* __restrict__ out) {
  const int lane = threadIdx.x & 63;
  const int row = blockIdx.x * 4 + (threadIdx.x >> 6);
  if (row >= NNODES) return;
  const int s = offsets[row];
  const int e = offsets[row + 1];
  float ax = 0.f, ay = 0.f;
  for (int i = s; i < e; i++) {
    const int c = sCol[i];
    const float v = sVal[i];
    const unsigned h = H2[(size_t)c * 64 + lane];
    ax += v * __uint_as_float(h << 16);
    ay += v * __uint_as_float(h & 0xffff0000u);
  }
  float2 r;
  r.x = ax;
  r.y = ay;
  ((float2*)out)[(size_t)row * 64 + lane] = r;
}

extern "C" void kernel_launch(void* const* d_in, const int* in_sizes, int n_in,
                              void* d_out, int out_size, void* d_ws, size_t ws_size,
                              hipStream_t stream) {
  const float* X = (const float*)d_in[0];
  const int* erow = (const int*)d_in[1];
  const int* ecol = (const int*)d_in[2];
  const float* eval = (const float*)d_in[3];
  const float* W = (const float*)d_in[4];
  const float* bias = (const float*)d_in[5];
  float* out = (float*)d_out;

  char* ws = (char*)d_ws;
  size_t off = 0;
  auto alloc = [&](size_t bytes) -> char* {
    char* p = ws + off;
    off += (bytes + 255) & ~(size_t)255;
    return p;
  };
  unsigned short* Hb = (unsigned short*)alloc((size_t)NNODES * ODIM * 2);  // 25.6 MB
  short* Wb = (short*)alloc((size_t)ODIM * KDIM * 2);                      // 64 KB
  int* counts = (int*)alloc((size_t)NNODES * 4);
  int* chunkExcl = (int*)alloc((size_t)NNODES * 4);
  int* offsets = (int*)alloc((size_t)(NNODES + 1) * 4);
  int* cursor = (int*)alloc((size_t)NNODES * 4);
  int* blockSums = (int*)alloc((size_t)NB_SCAN * 4);
  int* blockBase = (int*)alloc((size_t)NB_SCAN * 4);
  int* sCol = (int*)alloc((size_t)NEDGES * 4);   // 6.4 MB
  float* sVal = (float*)alloc((size_t)NEDGES * 4);  // 6.4 MB

  hipMemsetAsync(counts, 0, (size_t)NNODES * 4, stream);
  conv_w_kernel<<<(ODIM * KDIM + 255) / 256, 256, 0, stream>>>(W, Wb);
  hist_kernel<<<(NEDGES + 255) / 256, 256, 0, stream>>>(erow, counts);
  scan1_kernel<<<NB_SCAN, 256, 0, stream>>>(counts, chunkExcl, blockSums);
  scan2_kernel<<<1, 128, 0, stream>>>(blockSums, blockBase, offsets);
  scan3_kernel<<<(NNODES + 255) / 256, 256, 0, stream>>>(chunkExcl, blockBase, offsets, cursor);
  scatter_kernel<<<(NEDGES + 255) / 256, 256, 0, stream>>>(erow, ecol, eval, cursor, sCol, sVal);
  gemm_kernel<<<(NNODES + 63) / 64, 256, 0, stream>>>(X, Wb, bias, Hb);
  spmm_kernel<<<(NNODES + 3) / 4, 256, 0, stream>>>(offsets, sCol, sVal, (const unsigned*)Hb, out);
}

// Round 2
// 455.100 us; speedup vs baseline: 1.1946x; 1.1946x over previous
//
#include <hip/hip_runtime.h>
#include <hip/hip_bf16.h>

#define NNODES 100000
#define NEDGES 1600000
#define KDIM 256
#define ODIM 128
#define NB_SCAN 98        // ceil(100000 / 1024)
#define EDGE_CAP 1900032  // 1.6M + 3*100000, rounded up a bit

typedef __attribute__((ext_vector_type(8))) short short8;
typedef __attribute__((ext_vector_type(4))) float floatx4;

// round-to-nearest-even f32 -> bf16 (inputs are finite Gaussians; no NaN handling needed)
static __device__ __forceinline__ short f2bf(float f) {
  union { float f; unsigned u; } x; x.f = f;
  unsigned r = (x.u + 0x7fffu + ((x.u >> 16) & 1u)) >> 16;
  return (short)r;
}

__global__ void conv_w_kernel(const float* __restrict__ W, short* __restrict__ Wb) {
  int i = blockIdx.x * 256 + threadIdx.x;
  if (i < ODIM * KDIM) Wb[i] = f2bf(W[i]);
}

__global__ void hist_kernel(const int* __restrict__ rows, int* __restrict__ counts) {
  int i = blockIdx.x * 256 + threadIdx.x;
  if (i < NEDGES) atomicAdd(&counts[rows[i]], 1);
}

// per-1024-chunk exclusive scan of PADDED counts ((c+3)&~3) + chunk totals
__global__ void scan1_kernel(const int* __restrict__ counts, int* __restrict__ chunkExcl,
                             int* __restrict__ blockSums) {
  __shared__ int s[256];
  int t = threadIdx.x;
  int base = blockIdx.x * 1024 + t * 4;
  int v[4];
#pragma unroll
  for (int j = 0; j < 4; j++) {
    int idx = base + j;
    v[j] = (idx < NNODES) ? ((counts[idx] + 3) & ~3) : 0;  // pad to multiple of 4
  }
  int sum = v[0] + v[1] + v[2] + v[3];
  s[t] = sum;
  __syncthreads();
  for (int o = 1; o < 256; o <<= 1) {
    int add = (t >= o) ? s[t - o] : 0;
    __syncthreads();
    s[t] += add;
    __syncthreads();
  }
  int run = s[t] - sum;
#pragma unroll
  for (int j = 0; j < 4; j++) {
    int idx = base + j;
    if (idx < NNODES) chunkExcl[idx] = run;
    run += v[j];
  }
  if (t == 255) blockSums[blockIdx.x] = s[255];
}

// single-block exclusive scan of the 98 chunk totals; also writes offsets[NNODES] = total
__global__ void scan2_kernel(const int* __restrict__ blockSums, int* __restrict__ blockBase,
                             int* __restrict__ offsets) {
  __shared__ int s[128];
  int t = threadIdx.x;
  int v = (t < NB_SCAN) ? blockSums[t] : 0;
  s[t] = v;
  __syncthreads();
  for (int o = 1; o < 128; o <<= 1) {
    int add = (t >= o) ? s[t - o] : 0;
    __syncthreads();
    s[t] += add;
    __syncthreads();
  }
  if (t < NB_SCAN) blockBase[t] = s[t] - v;
  if (t == 127) offsets[NNODES] = s[127];
}

__global__ void scan3_kernel(const int* __restrict__ chunkExcl, const int* __restrict__ blockBase,
                             int* __restrict__ offsets, int* __restrict__ cursor) {
  int i = blockIdx.x * 256 + threadIdx.x;
  if (i < NNODES) {
    int o = chunkExcl[i] + blockBase[i >> 10];
    offsets[i] = o;
    cursor[i] = o;
  }
}

// packed edge record: int2{col, val_bits}; single 8 B scattered store
__global__ void scatter_kernel(const int* __restrict__ rows, const int* __restrict__ cols,
                               const float* __restrict__ vals, int* __restrict__ cursor,
                               int2* __restrict__ edges) {
  int i = blockIdx.x * 256 + threadIdx.x;
  if (i < NEDGES) {
    int r = rows[i];
    int p = atomicAdd(&cursor[r], 1);
    int2 rec;
    rec.x = cols[i];
    rec.y = __float_as_int(vals[i]);
    edges[p] = rec;
  }
}

// H = bf16(X @ W^T + b). Block = 256 (4 waves); wave owns a 32-row strip, all 8 n-tiles.
// A-frag: X[m][k0 + quad*8 + j] (fp32 load + cvt), two m-halves (l16, l16+16).
// B-frag: Wb[n = t*16+l16][k0 + quad*8 + j] (16 B bf16 load) — amortized over 2 MFMAs.
// D: col = lane&15, row = quad*4 + reg  [m89-verified layout]
__global__ __launch_bounds__(256) void gemm_kernel(const float* __restrict__ X,
                                                   const short* __restrict__ Wb,
                                                   const float* __restrict__ bias,
                                                   unsigned short* __restrict__ H) {
  const int lane = threadIdx.x & 63;
  const int wave = threadIdx.x >> 6;
  const int l16 = lane & 15;
  const int quad = lane >> 4;
  const int rowBase = blockIdx.x * 128 + wave * 32;
  const int arow0 = rowBase + l16;
  const int arow1 = arow0 + 16;

  floatx4 acc[8][2];
#pragma unroll
  for (int t = 0; t < 8; t++) {
    acc[t][0] = (floatx4){0.f, 0.f, 0.f, 0.f};
    acc[t][1] = (floatx4){0.f, 0.f, 0.f, 0.f};
  }

  for (int k0 = 0; k0 < KDIM; k0 += 32) {
    const int k = k0 + quad * 8;
    short8 a0, a1;
    if (arow0 < NNODES) {
      const float4* xp = (const float4*)(X + (size_t)arow0 * KDIM + k);
      float4 x0 = xp[0];
      float4 x1 = xp[1];
      a0[0] = f2bf(x0.x); a0[1] = f2bf(x0.y); a0[2] = f2bf(x0.z); a0[3] = f2bf(x0.w);
      a0[4] = f2bf(x1.x); a0[5] = f2bf(x1.y); a0[6] = f2bf(x1.z); a0[7] = f2bf(x1.w);
    } else {
      a0 = (short8){0, 0, 0, 0, 0, 0, 0, 0};
    }
    if (arow1 < NNODES) {
      const float4* xp = (const float4*)(X + (size_t)arow1 * KDIM + k);
      float4 x0 = xp[0];
      float4 x1 = xp[1];
      a1[0] = f2bf(x0.x); a1[1] = f2bf(x0.y); a1[2] = f2bf(x0.z); a1[3] = f2bf(x0.w);
      a1[4] = f2bf(x1.x); a1[5] = f2bf(x1.y); a1[6] = f2bf(x1.z); a1[7] = f2bf(x1.w);
    } else {
      a1 = (short8){0, 0, 0, 0, 0, 0, 0, 0};
    }
#pragma unroll
    for (int t = 0; t < 8; t++) {
      short8 b = *(const short8*)(Wb + (t * 16 + l16) * KDIM + k);
      acc[t][0] = __builtin_amdgcn_mfma_f32_16x16x32_bf16(a0, b, acc[t][0], 0, 0, 0);
      acc[t][1] = __builtin_amdgcn_mfma_f32_16x16x32_bf16(a1, b, acc[t][1], 0, 0, 0);
    }
  }

#pragma unroll
  for (int t = 0; t < 8; t++) {
    const int col = t * 16 + l16;
    const float bv = bias[col];
#pragma unroll
    for (int h = 0; h < 2; h++) {
#pragma unroll
      for (int r = 0; r < 4; r++) {
        const int row = rowBase + h * 16 + quad * 4 + r;
        if (row < NNODES) H[(size_t)row * ODIM + col] = (unsigned short)f2bf(acc[t][h][r] + bv);
      }
    }
  }
}

// One wave per output row. Lane owns channels {2*lane, 2*lane+1} (one uint = 2 bf16
// per gathered H row -> 256 B coalesced per edge). Segments are padded to a multiple
// of 4 records (pad = {col 0, val 0}) -> no tail loop; 4 gathers in flight per iter.
__global__ __launch_bounds__(256) void spmm_kernel(const int* __restrict__ offsets,
                                                   const int2* __restrict__ edges,
                                                   const unsigned* __restrict__ H2,
                                                   float* __restrict__ out) {
  const int lane = threadIdx.x & 63;
  const int row = blockIdx.x * 4 + (threadIdx.x >> 6);
  if (row >= NNODES) return;
  const int s = offsets[row];      // multiple of 4
  const int e = offsets[row + 1];
  float ax = 0.f, ay = 0.f;
  for (int i = s; i < e; i += 4) {
    const int4 p01 = *(const int4*)(edges + i);      // 16 B aligned (s % 4 == 0)
    const int4 p23 = *(const int4*)(edges + i + 2);
    const unsigned h0 = H2[(size_t)p01.x * 64 + lane];
    const unsigned h1 = H2[(size_t)p01.z * 64 + lane];
    const unsigned h2 = H2[(size_t)p23.x * 64 + lane];
    const unsigned h3 = H2[(size_t)p23.z * 64 + lane];
    const float v0 = __int_as_float(p01.y);
    const float v1 = __int_as_float(p01.w);
    const float v2 = __int_as_float(p23.y);
    const float v3 = __int_as_float(p23.w);
    ax += v0 * __uint_as_float(h0 << 16);
    ay += v0 * __uint_as_float(h0 & 0xffff0000u);
    ax += v1 * __uint_as_float(h1 << 16);
    ay += v1 * __uint_as_float(h1 & 0xffff0000u);
    ax += v2 * __uint_as_float(h2 << 16);
    ay += v2 * __uint_as_float(h2 & 0xffff0000u);
    ax += v3 * __uint_as_float(h3 << 16);
    ay += v3 * __uint_as_float(h3 & 0xffff0000u);
  }
  float2 r;
  r.x = ax;
  r.y = ay;
  ((float2*)out)[(size_t)row * 64 + lane] = r;
}

extern "C" void kernel_launch(void* const* d_in, const int* in_sizes, int n_in,
                              void* d_out, int out_size, void* d_ws, size_t ws_size,
                              hipStream_t stream) {
  const float* X = (const float*)d_in[0];
  const int* erow = (const int*)d_in[1];
  const int* ecol = (const int*)d_in[2];
  const float* eval = (const float*)d_in[3];
  const float* W = (const float*)d_in[4];
  const float* bias = (const float*)d_in[5];
  float* out = (float*)d_out;

  char* ws = (char*)d_ws;
  size_t off = 0;
  auto alloc = [&](size_t bytes) -> char* {
    char* p = ws + off;
    off += (bytes + 255) & ~(size_t)255;
    return p;
  };
  unsigned short* Hb = (unsigned short*)alloc((size_t)NNODES * ODIM * 2);  // 25.6 MB
  short* Wb = (short*)alloc((size_t)ODIM * KDIM * 2);                      // 64 KB
  int* counts = (int*)alloc((size_t)NNODES * 4);
  int* chunkExcl = (int*)alloc((size_t)NNODES * 4);
  int* offsets = (int*)alloc((size_t)(NNODES + 1) * 4);
  int* cursor = (int*)alloc((size_t)NNODES * 4);
  int* blockSums = (int*)alloc((size_t)NB_SCAN * 4);
  int* blockBase = (int*)alloc((size_t)NB_SCAN * 4);
  int2* edges = (int2*)alloc((size_t)EDGE_CAP * 8);  // 15.2 MB, padded CSR records

  hipMemsetAsync(counts, 0, (size_t)NNODES * 4, stream);
  hipMemsetAsync(edges, 0, (size_t)EDGE_CAP * 8, stream);  // pad records = {col 0, val 0}
  conv_w_kernel<<<(ODIM * KDIM + 255) / 256, 256, 0, stream>>>(W, Wb);
  hist_kernel<<<(NEDGES + 255) / 256, 256, 0, stream>>>(erow, counts);
  scan1_kernel<<<NB_SCAN, 256, 0, stream>>>(counts, chunkExcl, blockSums);
  scan2_kernel<<<1, 128, 0, stream>>>(blockSums, blockBase, offsets);
  scan3_kernel<<<(NNODES + 255) / 256, 256, 0, stream>>>(chunkExcl, blockBase, offsets, cursor);
  scatter_kernel<<<(NEDGES + 255) / 256, 256, 0, stream>>>(erow, ecol, eval, cursor, edges);
  gemm_kernel<<<(NNODES + 127) / 128, 256, 0, stream>>>(X, Wb, bias, Hb);
  spmm_kernel<<<(NNODES + 3) / 4, 256, 0, stream>>>(offsets, edges, (const unsigned*)Hb, out);
}

// Round 3
// 411.921 us; speedup vs baseline: 1.3198x; 1.1048x over previous
//
#include <hip/hip_runtime.h>
#include <hip/hip_bf16.h>

#define NNODES 100000
#define NEDGES 1600000
#define KDIM 256
#define ODIM 128
#define NB_SCAN 98        // ceil(100000 / 1024)
#define EDGE_CAP 1900032  // 1.6M + 3*100000, rounded up a bit
#define ESTRIDE 400000    // NEDGES / 4

typedef __attribute__((ext_vector_type(8))) short short8;
typedef __attribute__((ext_vector_type(4))) float floatx4;

// round-to-nearest-even f32 -> bf16 (inputs are finite Gaussians; no NaN handling needed)
static __device__ __forceinline__ short f2bf(float f) {
  union { float f; unsigned u; } x; x.f = f;
  unsigned r = (x.u + 0x7fffu + ((x.u >> 16) & 1u)) >> 16;
  return (short)r;
}

__global__ void conv_w_kernel(const float* __restrict__ W, short* __restrict__ Wb) {
  int i = blockIdx.x * 256 + threadIdx.x;
  if (i < ODIM * KDIM) Wb[i] = f2bf(W[i]);
}

// Fused histogram + rank assignment: counts[] becomes the degree histogram,
// rank[e] is edge e's arrival index within its row (coalesced ushort store —
// max degree for Poisson(16) over 100k rows is ~50, ushort is ample).
// 4 edges per thread = 4 independent atomic chains in flight.
__global__ void rank_kernel(const int* __restrict__ rows, int* __restrict__ counts,
                            unsigned short* __restrict__ rank) {
  int i = blockIdx.x * 256 + threadIdx.x;
#pragma unroll
  for (int j = 0; j < 4; j++) {
    int e = i + j * ESTRIDE;
    if (e < NEDGES) {
      int r = rows[e];
      rank[e] = (unsigned short)atomicAdd(&counts[r], 1);
    }
  }
}

// per-1024-chunk exclusive scan of PADDED counts ((c+3)&~3) + chunk totals
__global__ void scan1_kernel(const int* __restrict__ counts, int* __restrict__ chunkExcl,
                             int* __restrict__ blockSums) {
  __shared__ int s[256];
  int t = threadIdx.x;
  int base = blockIdx.x * 1024 + t * 4;
  int v[4];
#pragma unroll
  for (int j = 0; j < 4; j++) {
    int idx = base + j;
    v[j] = (idx < NNODES) ? ((counts[idx] + 3) & ~3) : 0;  // pad to multiple of 4
  }
  int sum = v[0] + v[1] + v[2] + v[3];
  s[t] = sum;
  __syncthreads();
  for (int o = 1; o < 256; o <<= 1) {
    int add = (t >= o) ? s[t - o] : 0;
    __syncthreads();
    s[t] += add;
    __syncthreads();
  }
  int run = s[t] - sum;
#pragma unroll
  for (int j = 0; j < 4; j++) {
    int idx = base + j;
    if (idx < NNODES) chunkExcl[idx] = run;
    run += v[j];
  }
  if (t == 255) blockSums[blockIdx.x] = s[255];
}

// single-block exclusive scan of the 98 chunk totals; also writes offsets[NNODES] = total
__global__ void scan2_kernel(const int* __restrict__ blockSums, int* __restrict__ blockBase,
                             int* __restrict__ offsets) {
  __shared__ int s[128];
  int t = threadIdx.x;
  int v = (t < NB_SCAN) ? blockSums[t] : 0;
  s[t] = v;
  __syncthreads();
  for (int o = 1; o < 128; o <<= 1) {
    int add = (t >= o) ? s[t - o] : 0;
    __syncthreads();
    s[t] += add;
    __syncthreads();
  }
  if (t < NB_SCAN) blockBase[t] = s[t] - v;
  if (t == 127) offsets[NNODES] = s[127];
}

__global__ void scan3_kernel(const int* __restrict__ chunkExcl, const int* __restrict__ blockBase,
                             int* __restrict__ offsets) {
  int i = blockIdx.x * 256 + threadIdx.x;
  if (i < NNODES) offsets[i] = chunkExcl[i] + blockBase[i >> 10];
}

// Atomic-free placement: pos = offsets[row] + rank. offsets is 400 KB (L2-resident
// random read); the scattered 8 B store has no RMW dependency -> pipelines freely.
__global__ void place_kernel(const int* __restrict__ rows, const int* __restrict__ cols,
                             const float* __restrict__ vals,
                             const unsigned short* __restrict__ rank,
                             const int* __restrict__ offsets, int2* __restrict__ edges) {
  int i = blockIdx.x * 256 + threadIdx.x;
#pragma unroll
  for (int j = 0; j < 4; j++) {
    int e = i + j * ESTRIDE;
    if (e < NEDGES) {
      int r = rows[e];
      int p = offsets[r] + (int)rank[e];
      int2 rec;
      rec.x = cols[e];
      rec.y = __float_as_int(vals[e]);
      edges[p] = rec;
    }
  }
}

// H = bf16(X @ W^T + b). Block = 256 (4 waves); wave owns a 32-row strip, all 8 n-tiles.
// A-frag: X[m][k0 + quad*8 + j] (fp32 load + cvt), two m-halves (l16, l16+16).
// B-frag: Wb[n = t*16+l16][k0 + quad*8 + j] (16 B bf16 load) — amortized over 2 MFMAs.
// D: col = lane&15, row = quad*4 + reg  [m89-verified layout]
__global__ __launch_bounds__(256) void gemm_kernel(const float* __restrict__ X,
                                                   const short* __restrict__ Wb,
                                                   const float* __restrict__ bias,
                                                   unsigned short* __restrict__ H) {
  const int lane = threadIdx.x & 63;
  const int wave = threadIdx.x >> 6;
  const int l16 = lane & 15;
  const int quad = lane >> 4;
  const int rowBase = blockIdx.x * 128 + wave * 32;
  const int arow0 = rowBase + l16;
  const int arow1 = arow0 + 16;

  floatx4 acc[8][2];
#pragma unroll
  for (int t = 0; t < 8; t++) {
    acc[t][0] = (floatx4){0.f, 0.f, 0.f, 0.f};
    acc[t][1] = (floatx4){0.f, 0.f, 0.f, 0.f};
  }

  for (int k0 = 0; k0 < KDIM; k0 += 32) {
    const int k = k0 + quad * 8;
    short8 a0, a1;
    if (arow0 < NNODES) {
      const float4* xp = (const float4*)(X + (size_t)arow0 * KDIM + k);
      float4 x0 = xp[0];
      float4 x1 = xp[1];
      a0[0] = f2bf(x0.x); a0[1] = f2bf(x0.y); a0[2] = f2bf(x0.z); a0[3] = f2bf(x0.w);
      a0[4] = f2bf(x1.x); a0[5] = f2bf(x1.y); a0[6] = f2bf(x1.z); a0[7] = f2bf(x1.w);
    } else {
      a0 = (short8){0, 0, 0, 0, 0, 0, 0, 0};
    }
    if (arow1 < NNODES) {
      const float4* xp = (const float4*)(X + (size_t)arow1 * KDIM + k);
      float4 x0 = xp[0];
      float4 x1 = xp[1];
      a1[0] = f2bf(x0.x); a1[1] = f2bf(x0.y); a1[2] = f2bf(x0.z); a1[3] = f2bf(x0.w);
      a1[4] = f2bf(x1.x); a1[5] = f2bf(x1.y); a1[6] = f2bf(x1.z); a1[7] = f2bf(x1.w);
    } else {
      a1 = (short8){0, 0, 0, 0, 0, 0, 0, 0};
    }
#pragma unroll
    for (int t = 0; t < 8; t++) {
      short8 b = *(const short8*)(Wb + (t * 16 + l16) * KDIM + k);
      acc[t][0] = __builtin_amdgcn_mfma_f32_16x16x32_bf16(a0, b, acc[t][0], 0, 0, 0);
      acc[t][1] = __builtin_amdgcn_mfma_f32_16x16x32_bf16(a1, b, acc[t][1], 0, 0, 0);
    }
  }

#pragma unroll
  for (int t = 0; t < 8; t++) {
    const int col = t * 16 + l16;
    const float bv = bias[col];
#pragma unroll
    for (int h = 0; h < 2; h++) {
#pragma unroll
      for (int r = 0; r < 4; r++) {
        const int row = rowBase + h * 16 + quad * 4 + r;
        if (row < NNODES) H[(size_t)row * ODIM + col] = (unsigned short)f2bf(acc[t][h][r] + bv);
      }
    }
  }
}

// One wave per output row. Lane owns channels {2*lane, 2*lane+1} (one uint = 2 bf16
// per gathered H row -> 256 B coalesced per edge). Segments are padded to a multiple
// of 4 records (pad = {col 0, val 0}) -> no tail loop; 4 gathers in flight per iter.
__global__ __launch_bounds__(256) void spmm_kernel(const int* __restrict__ offsets,
                                                   const int2* __restrict__ edges,
                                                   const unsigned* __restrict__ H2,
                                                   float* __restrict__ out) {
  const int lane = threadIdx.x & 63;
  const int row = blockIdx.x * 4 + (threadIdx.x >> 6);
  if (row >= NNODES) return;
  const int s = offsets[row];      // multiple of 4
  const int e = offsets[row + 1];
  float ax = 0.f, ay = 0.f;
  for (int i = s; i < e; i += 4) {
    const int4 p01 = *(const int4*)(edges + i);      // 16 B aligned (s % 4 == 0)
    const int4 p23 = *(const int4*)(edges + i + 2);
    const unsigned h0 = H2[(size_t)p01.x * 64 + lane];
    const unsigned h1 = H2[(size_t)p01.z * 64 + lane];
    const unsigned h2 = H2[(size_t)p23.x * 64 + lane];
    const unsigned h3 = H2[(size_t)p23.z * 64 + lane];
    const float v0 = __int_as_float(p01.y);
    const float v1 = __int_as_float(p01.w);
    const float v2 = __int_as_float(p23.y);
    const float v3 = __int_as_float(p23.w);
    ax += v0 * __uint_as_float(h0 << 16);
    ay += v0 * __uint_as_float(h0 & 0xffff0000u);
    ax += v1 * __uint_as_float(h1 << 16);
    ay += v1 * __uint_as_float(h1 & 0xffff0000u);
    ax += v2 * __uint_as_float(h2 << 16);
    ay += v2 * __uint_as_float(h2 & 0xffff0000u);
    ax += v3 * __uint_as_float(h3 << 16);
    ay += v3 * __uint_as_float(h3 & 0xffff0000u);
  }
  float2 r;
  r.x = ax;
  r.y = ay;
  ((float2*)out)[(size_t)row * 64 + lane] = r;
}

extern "C" void kernel_launch(void* const* d_in, const int* in_sizes, int n_in,
                              void* d_out, int out_size, void* d_ws, size_t ws_size,
                              hipStream_t stream) {
  const float* X = (const float*)d_in[0];
  const int* erow = (const int*)d_in[1];
  const int* ecol = (const int*)d_in[2];
  const float* eval = (const float*)d_in[3];
  const float* W = (const float*)d_in[4];
  const float* bias = (const float*)d_in[5];
  float* out = (float*)d_out;

  char* ws = (char*)d_ws;
  size_t off = 0;
  auto alloc = [&](size_t bytes) -> char* {
    char* p = ws + off;
    off += (bytes + 255) & ~(size_t)255;
    return p;
  };
  unsigned short* Hb = (unsigned short*)alloc((size_t)NNODES * ODIM * 2);  // 25.6 MB
  short* Wb = (short*)alloc((size_t)ODIM * KDIM * 2);                      // 64 KB
  int* counts = (int*)alloc((size_t)NNODES * 4);
  int* chunkExcl = (int*)alloc((size_t)NNODES * 4);
  int* offsets = (int*)alloc((size_t)(NNODES + 1) * 4);
  int* blockSums = (int*)alloc((size_t)NB_SCAN * 4);
  int* blockBase = (int*)alloc((size_t)NB_SCAN * 4);
  unsigned short* rank = (unsigned short*)alloc((size_t)NEDGES * 2);  // 3.2 MB
  int2* edges = (int2*)alloc((size_t)EDGE_CAP * 8);  // 15.2 MB, padded CSR records

  hipMemsetAsync(counts, 0, (size_t)NNODES * 4, stream);
  hipMemsetAsync(edges, 0, (size_t)EDGE_CAP * 8, stream);  // pad records = {col 0, val 0}
  conv_w_kernel<<<(ODIM * KDIM + 255) / 256, 256, 0, stream>>>(W, Wb);
  rank_kernel<<<(ESTRIDE + 255) / 256, 256, 0, stream>>>(erow, counts, rank);
  scan1_kernel<<<NB_SCAN, 256, 0, stream>>>(counts, chunkExcl, blockSums);
  scan2_kernel<<<1, 128, 0, stream>>>(blockSums, blockBase, offsets);
  scan3_kernel<<<(NNODES + 255) / 256, 256, 0, stream>>>(chunkExcl, blockBase, offsets);
  place_kernel<<<(ESTRIDE + 255) / 256, 256, 0, stream>>>(erow, ecol, eval, rank, offsets, edges);
  gemm_kernel<<<(NNODES + 127) / 128, 256, 0, stream>>>(X, Wb, bias, Hb);
  spmm_kernel<<<(NNODES + 3) / 4, 256, 0, stream>>>(offsets, edges, (const unsigned*)Hb, out);
}

// Round 4
// 386.113 us; speedup vs baseline: 1.4081x; 1.0668x over previous
//
#include <hip/hip_runtime.h>
#include <hip/hip_bf16.h>

#define NNODES 100000
#define NEDGES 1600000
#define KDIM 256
#define ODIM 128
#define NB_SCAN 98        // ceil(100000 / 1024)
#define EDGE_CAP 1900032  // 1.6M + 3*100000, rounded up a bit
#define ESTRIDE 400000    // NEDGES / 4
#define GEMM_BLOCKS 1563  // ceil(100000 / 64)
#define RANK_BLOCKS 1563  // ceil(400000 / 256)

typedef __attribute__((ext_vector_type(8))) short short8;
typedef __attribute__((ext_vector_type(4))) float floatx4;

// round-to-nearest-even f32 -> bf16 (inputs are finite Gaussians; no NaN handling needed)
static __device__ __forceinline__ short f2bf(float f) {
  union { float f; unsigned u; } x; x.f = f;
  unsigned r = (x.u + 0x7fffu + ((x.u >> 16) & 1u)) >> 16;
  return (short)r;
}

__global__ void conv_w_kernel(const float* __restrict__ W, short* __restrict__ Wb) {
  int i = blockIdx.x * 256 + threadIdx.x;
  if (i < ODIM * KDIM) Wb[i] = f2bf(W[i]);
}

// per-1024-chunk exclusive scan of PADDED counts ((c+3)&~3) + chunk totals
__global__ void scan1_kernel(const int* __restrict__ counts, int* __restrict__ chunkExcl,
                             int* __restrict__ blockSums) {
  __shared__ int s[256];
  int t = threadIdx.x;
  int base = blockIdx.x * 1024 + t * 4;
  int v[4];
#pragma unroll
  for (int j = 0; j < 4; j++) {
    int idx = base + j;
    v[j] = (idx < NNODES) ? ((counts[idx] + 3) & ~3) : 0;  // pad to multiple of 4
  }
  int sum = v[0] + v[1] + v[2] + v[3];
  s[t] = sum;
  __syncthreads();
  for (int o = 1; o < 256; o <<= 1) {
    int add = (t >= o) ? s[t - o] : 0;
    __syncthreads();
    s[t] += add;
    __syncthreads();
  }
  int run = s[t] - sum;
#pragma unroll
  for (int j = 0; j < 4; j++) {
    int idx = base + j;
    if (idx < NNODES) chunkExcl[idx] = run;
    run += v[j];
  }
  if (t == 255) blockSums[blockIdx.x] = s[255];
}

// single-block exclusive scan of the 98 chunk totals; also writes offsets[NNODES] = total
__global__ void scan2_kernel(const int* __restrict__ blockSums, int* __restrict__ blockBase,
                             int* __restrict__ offsets) {
  __shared__ int s[128];
  int t = threadIdx.x;
  int v = (t < NB_SCAN) ? blockSums[t] : 0;
  s[t] = v;
  __syncthreads();
  for (int o = 1; o < 128; o <<= 1) {
    int add = (t >= o) ? s[t - o] : 0;
    __syncthreads();
    s[t] += add;
    __syncthreads();
  }
  if (t < NB_SCAN) blockBase[t] = s[t] - v;
  if (t == 127) offsets[NNODES] = s[127];
}

__global__ void scan3_kernel(const int* __restrict__ chunkExcl, const int* __restrict__ blockBase,
                             int* __restrict__ offsets) {
  int i = blockIdx.x * 256 + threadIdx.x;
  if (i < NNODES) offsets[i] = chunkExcl[i] + blockBase[i >> 10];
}

// Atomic-free placement: pos = offsets[row] + rank. offsets is 400 KB (L2-resident
// random read); the scattered 8 B store has no RMW dependency -> pipelines freely.
__global__ void place_kernel(const int* __restrict__ rows, const int* __restrict__ cols,
                             const float* __restrict__ vals,
                             const unsigned short* __restrict__ rank,
                             const int* __restrict__ offsets, int2* __restrict__ edges) {
  int i = blockIdx.x * 256 + threadIdx.x;
#pragma unroll
  for (int j = 0; j < 4; j++) {
    int e = i + j * ESTRIDE;
    if (e < NEDGES) {
      int r = rows[e];
      int p = offsets[r] + (int)rank[e];
      int2 rec;
      rec.x = cols[e];
      rec.y = __float_as_int(vals[e]);
      edges[p] = rec;
    }
  }
}

// Fused: blocks [0, GEMM_BLOCKS) compute H = bf16(X @ W^T + b); blocks
// [GEMM_BLOCKS, +RANK_BLOCKS) run the histogram+rank atomics. The rank work is
// pure atomic-latency (0.4% VALU) and hides under the gemm's HBM streaming.
//
// gemm: 64 rows/block, 16 rows/wave, all 8 n-tiles per wave. K-loop fully
// unrolled with register double-buffer on the X loads (2x float4 per lane per
// k-step). A-frag: X[m=l16][k0*32 + quad*8 + j]; B-frag: Wb[n=t*16+l16][same k]
// (L2-resident, 64 KB). D: col = lane&15, row = quad*4 + reg  [m89 layout]
__global__ __launch_bounds__(256) void gemm_rank_kernel(
    const float* __restrict__ X, const short* __restrict__ Wb,
    const float* __restrict__ bias, unsigned short* __restrict__ H,
    const int* __restrict__ rows, int* __restrict__ counts,
    unsigned short* __restrict__ rank) {
  if (blockIdx.x >= GEMM_BLOCKS) {
    // ---- rank path: 4 independent atomic chains per thread ----
    int i = (blockIdx.x - GEMM_BLOCKS) * 256 + threadIdx.x;
#pragma unroll
    for (int j = 0; j < 4; j++) {
      int e = i + j * ESTRIDE;
      if (e < NEDGES) {
        int r = rows[e];
        rank[e] = (unsigned short)atomicAdd(&counts[r], 1);
      }
    }
    return;
  }
  // ---- gemm path ----
  const int lane = threadIdx.x & 63;
  const int wave = threadIdx.x >> 6;
  const int l16 = lane & 15;
  const int quad = lane >> 4;
  const int rowBase = blockIdx.x * 64 + wave * 16;
  const int arow = rowBase + l16;
  const bool inb = arow < NNODES;
  const float4 zf4 = {0.f, 0.f, 0.f, 0.f};
  // lane's X stream: row arow, starting at k = quad*8; k-step stride = 32 floats
  const float4* xp = (const float4*)(X + (size_t)(inb ? arow : 0) * KDIM + quad * 8);

  floatx4 acc[8];
#pragma unroll
  for (int t = 0; t < 8; t++) acc[t] = (floatx4){0.f, 0.f, 0.f, 0.f};

  float4 c0 = inb ? xp[0] : zf4;
  float4 c1 = inb ? xp[1] : zf4;
#pragma unroll
  for (int k0 = 0; k0 < 8; k0++) {
    float4 n0, n1;
    if (k0 < 7) {
      n0 = inb ? xp[(k0 + 1) * 8] : zf4;
      n1 = inb ? xp[(k0 + 1) * 8 + 1] : zf4;
    }
    short8 a;
    a[0] = f2bf(c0.x); a[1] = f2bf(c0.y); a[2] = f2bf(c0.z); a[3] = f2bf(c0.w);
    a[4] = f2bf(c1.x); a[5] = f2bf(c1.y); a[6] = f2bf(c1.z); a[7] = f2bf(c1.w);
    const short* bp = Wb + k0 * 32 + quad * 8;
#pragma unroll
    for (int t = 0; t < 8; t++) {
      short8 b = *(const short8*)(bp + (size_t)(t * 16 + l16) * KDIM);
      acc[t] = __builtin_amdgcn_mfma_f32_16x16x32_bf16(a, b, acc[t], 0, 0, 0);
    }
    if (k0 < 7) { c0 = n0; c1 = n1; }
  }

#pragma unroll
  for (int t = 0; t < 8; t++) {
    const int col = t * 16 + l16;
    const float bv = bias[col];
#pragma unroll
    for (int r = 0; r < 4; r++) {
      const int row = rowBase + quad * 4 + r;
      if (row < NNODES) H[(size_t)row * ODIM + col] = (unsigned short)f2bf(acc[t][r] + bv);
    }
  }
}

// One wave per output row. Lane owns channels {2*lane, 2*lane+1} (one uint = 2 bf16
// per gathered H row -> 256 B coalesced per edge). Segments are padded to a multiple
// of 4 records (pad = {col 0, val 0}) -> no tail loop; 4 gathers in flight per iter.
__global__ __launch_bounds__(256) void spmm_kernel(const int* __restrict__ offsets,
                                                   const int2* __restrict__ edges,
                                                   const unsigned* __restrict__ H2,
                                                   float* __restrict__ out) {
  const int lane = threadIdx.x & 63;
  const int row = blockIdx.x * 4 + (threadIdx.x >> 6);
  if (row >= NNODES) return;
  const int s = offsets[row];      // multiple of 4
  const int e = offsets[row + 1];
  float ax = 0.f, ay = 0.f;
  for (int i = s; i < e; i += 4) {
    const int4 p01 = *(const int4*)(edges + i);      // 16 B aligned (s % 4 == 0)
    const int4 p23 = *(const int4*)(edges + i + 2);
    const unsigned h0 = H2[(size_t)p01.x * 64 + lane];
    const unsigned h1 = H2[(size_t)p01.z * 64 + lane];
    const unsigned h2 = H2[(size_t)p23.x * 64 + lane];
    const unsigned h3 = H2[(size_t)p23.z * 64 + lane];
    const float v0 = __int_as_float(p01.y);
    const float v1 = __int_as_float(p01.w);
    const float v2 = __int_as_float(p23.y);
    const float v3 = __int_as_float(p23.w);
    ax += v0 * __uint_as_float(h0 << 16);
    ay += v0 * __uint_as_float(h0 & 0xffff0000u);
    ax += v1 * __uint_as_float(h1 << 16);
    ay += v1 * __uint_as_float(h1 & 0xffff0000u);
    ax += v2 * __uint_as_float(h2 << 16);
    ay += v2 * __uint_as_float(h2 & 0xffff0000u);
    ax += v3 * __uint_as_float(h3 << 16);
    ay += v3 * __uint_as_float(h3 & 0xffff0000u);
  }
  float2 r;
  r.x = ax;
  r.y = ay;
  ((float2*)out)[(size_t)row * 64 + lane] = r;
}

extern "C" void kernel_launch(void* const* d_in, const int* in_sizes, int n_in,
                              void* d_out, int out_size, void* d_ws, size_t ws_size,
                              hipStream_t stream) {
  const float* X = (const float*)d_in[0];
  const int* erow = (const int*)d_in[1];
  const int* ecol = (const int*)d_in[2];
  const float* eval = (const float*)d_in[3];
  const float* W = (const float*)d_in[4];
  const float* bias = (const float*)d_in[5];
  float* out = (float*)d_out;

  char* ws = (char*)d_ws;
  size_t off = 0;
  auto alloc = [&](size_t bytes) -> char* {
    char* p = ws + off;
    off += (bytes + 255) & ~(size_t)255;
    return p;
  };
  unsigned short* Hb = (unsigned short*)alloc((size_t)NNODES * ODIM * 2);  // 25.6 MB
  short* Wb = (short*)alloc((size_t)ODIM * KDIM * 2);                      // 64 KB
  int* counts = (int*)alloc((size_t)NNODES * 4);
  int* chunkExcl = (int*)alloc((size_t)NNODES * 4);
  int* offsets = (int*)alloc((size_t)(NNODES + 1) * 4);
  int* blockSums = (int*)alloc((size_t)NB_SCAN * 4);
  int* blockBase = (int*)alloc((size_t)NB_SCAN * 4);
  unsigned short* rank = (unsigned short*)alloc((size_t)NEDGES * 2);  // 3.2 MB
  int2* edges = (int2*)alloc((size_t)EDGE_CAP * 8);  // 15.2 MB, padded CSR records

  hipMemsetAsync(counts, 0, (size_t)NNODES * 4, stream);
  hipMemsetAsync(edges, 0, (size_t)EDGE_CAP * 8, stream);  // pad records = {col 0, val 0}
  conv_w_kernel<<<(ODIM * KDIM + 255) / 256, 256, 0, stream>>>(W, Wb);
  gemm_rank_kernel<<<GEMM_BLOCKS + RANK_BLOCKS, 256, 0, stream>>>(X, Wb, bias, Hb,
                                                                 erow, counts, rank);
  scan1_kernel<<<NB_SCAN, 256, 0, stream>>>(counts, chunkExcl, blockSums);
  scan2_kernel<<<1, 128, 0, stream>>>(blockSums, blockBase, offsets);
  scan3_kernel<<<(NNODES + 255) / 256, 256, 0, stream>>>(chunkExcl, blockBase, offsets);
  place_kernel<<<(ESTRIDE + 255) / 256, 256, 0, stream>>>(erow, ecol, eval, rank, offsets, edges);
  spmm_kernel<<<(NNODES + 3) / 4, 256, 0, stream>>>(offsets, edges, (const unsigned*)Hb, out);
}